// Round 5
// baseline (248.202 us; speedup 1.0000x reference)
//
#include <hip/hip_runtime.h>
#include <hip/hip_bf16.h>

// DSMoE: B=4,S=2048 -> T=8192 tokens, D=512, H=1024, E=8 routed (top-2) + shared.
// bf16 MFMA token-gather MoE; shared expert folded in as expert 8.
// R10: R9b (240us, XCD-pinned) + stage1/stage2 switched to mfma_32x32x16_bf16
//     (2x2 tiles of 32x32 per wave): ds_read count halves, MFMA cycles -17%,
//     less VALU addressing. w13 interleave moves to 32-col granules so silu
//     pairing stays in-lane (acc col-tile 0 = h1, tile 1 = h3). rcp-silu epilogue.

#define Tn 8192
#define Dd 512
#define Hh 1024
#define NEx 9

typedef __attribute__((ext_vector_type(8))) short short8;
typedef __attribute__((ext_vector_type(4))) float f32x4;
typedef __attribute__((ext_vector_type(16))) float f32x16;

#define AS1 __attribute__((address_space(1)))
#define AS3 __attribute__((address_space(3)))

#define OFF_XB    ((size_t)0)
#define OFF_W13T  (OFF_XB + (size_t)Tn * Dd * 2)
#define OFF_W2T   (OFF_W13T + (size_t)NEx * 2 * Hh * Dd * 2)
#define OFF_HBUF  (OFF_W2T + (size_t)NEx * Dd * Hh * 2)
#define OFF_TOK   (OFF_HBUF + (size_t)(3 * Tn) * Hh * 2)
#define OFF_SLOTP (OFF_TOK + (size_t)8 * Tn * 4)
#define OFF_PG    (OFF_SLOTP + (size_t)Tn * 2 * 4)
#define OFF_CNT   (OFF_PG + (size_t)Tn * 2 * 4)       // 8 counters, 128B apart
#define OFF_OFFS  (OFF_CNT + 1024)                    // off[9] then cntc[9]
#define OFF_YC    OFF_XB   // alias: Yc (25.2MB) over xb+w13t (26.9MB), dead by stage2

__device__ __forceinline__ ushort f2bf(float f) {
    unsigned int u = __float_as_uint(f);
    return (ushort)((u + 0x7fffu + ((u >> 16) & 1u)) >> 16);
}
__device__ __forceinline__ float bf2f(short s) {
    return __uint_as_float(((unsigned int)(unsigned short)s) << 16);
}

// ---------- fused transpose: 27 slices; fam 0/1 interleave into w13t ----------
// fam 0: w1, fam 1: w3 -> w13t rows n = ((h>>5)*2+fam)*32 + (h&31); fam 2: w2 plain.
__global__ __launch_bounds__(256) void trans_kernel(
        const float* __restrict__ w1, const float* __restrict__ sw1,
        const float* __restrict__ w3, const float* __restrict__ sw3,
        const float* __restrict__ w2, const float* __restrict__ sw2,
        ushort* __restrict__ w13t, ushort* __restrict__ w2t) {
    __shared__ float tile[32][33];
    int z = blockIdx.z;
    int fam = z / 9, sl = z - fam * 9;
    int tx = threadIdx.x & 31, ty = threadIdx.x >> 5;
    if (fam < 2) {
        const float* base = (fam == 0) ? ((sl < 8) ? w1 + (size_t)sl * Dd * Hh : sw1)
                                       : ((sl < 8) ? w3 + (size_t)sl * Dd * Hh : sw3);
        ushort* dst = w13t + (size_t)sl * 2 * Hh * Dd;
        int c0 = blockIdx.x * 32, r0 = blockIdx.y * 32;   // c: hidden, r: dim
#pragma unroll
        for (int k = 0; k < 4; ++k)
            tile[ty + 8 * k][tx] = base[(size_t)(r0 + ty + 8 * k) * Hh + c0 + tx];
        __syncthreads();
#pragma unroll
        for (int k = 0; k < 4; ++k) {
            int h = c0 + ty + 8 * k;
            int n = (((h >> 5) * 2 + fam) << 5) + (h & 31);
            dst[(size_t)n * Dd + r0 + tx] = f2bf(tile[tx][ty + 8 * k]);
        }
    } else {
        const float* base = (sl < 8) ? w2 + (size_t)sl * Dd * Hh : sw2;
        ushort* dst = w2t + (size_t)sl * Dd * Hh;
        int r0 = blockIdx.x * 32, c0 = blockIdx.y * 32;   // r: hidden, c: dim
#pragma unroll
        for (int k = 0; k < 4; ++k)
            tile[ty + 8 * k][tx] = base[(size_t)(r0 + ty + 8 * k) * Dd + c0 + tx];
        __syncthreads();
#pragma unroll
        for (int k = 0; k < 4; ++k)
            dst[(size_t)(c0 + ty + 8 * k) * Hh + r0 + tx] = f2bf(tile[tx][ty + 8 * k]);
    }
}

// ---------- router: 32 tokens/block, LDS-aggregated atomics; also emits xb + slot map ----------
__global__ __launch_bounds__(256) void router_kernel(const float* __restrict__ x,
                                                     const float* __restrict__ gw,
                                                     const float* __restrict__ bias,
                                                     int* __restrict__ cnt,     // padded: cnt[e*32]
                                                     int* __restrict__ tok,
                                                     int* __restrict__ slotp,
                                                     float* __restrict__ pg,
                                                     ushort* __restrict__ xb) {
    __shared__ int le[64];
    __shared__ float lg[64];
    __shared__ int lpos[64];
    __shared__ int lcnt[8];
    __shared__ int gbase[8];
    int tid = threadIdx.x, lane = tid & 63, wave = tid >> 6;
    if (tid < 8) lcnt[tid] = 0;
    __syncthreads();
    int t0 = blockIdx.x * 32 + wave * 8;
    for (int it = 0; it < 8; ++it) {
        int t = t0 + it;
        const float4* xr = (const float4*)(x + (size_t)t * Dd);
        float4 xa = xr[lane * 2], xc = xr[lane * 2 + 1];
        ushort4 o1, o2;
        o1.x = f2bf(xa.x); o1.y = f2bf(xa.y); o1.z = f2bf(xa.z); o1.w = f2bf(xa.w);
        o2.x = f2bf(xc.x); o2.y = f2bf(xc.y); o2.z = f2bf(xc.z); o2.w = f2bf(xc.w);
        *(ushort4*)(xb + (size_t)t * Dd + lane * 8) = o1;
        *(ushort4*)(xb + (size_t)t * Dd + lane * 8 + 4) = o2;
        float sc[8];
#pragma unroll
        for (int e = 0; e < 8; ++e) {
            const float4* gr = (const float4*)(gw + (size_t)e * Dd);
            float4 ga = gr[lane * 2], gc = gr[lane * 2 + 1];
            float s = xa.x * ga.x + xa.y * ga.y + xa.z * ga.z + xa.w * ga.w
                    + xc.x * gc.x + xc.y * gc.y + xc.z * gc.z + xc.w * gc.w;
#pragma unroll
            for (int o = 32; o > 0; o >>= 1) s += __shfl_xor(s, o);
            sc[e] = s;
        }
        if (lane == 0) {
            float b0 = -1e30f; int i0 = 0;
#pragma unroll
            for (int e = 0; e < 8; ++e) { float bv = sc[e] + bias[e]; if (bv > b0) { b0 = bv; i0 = e; } }
            float b1v = -1e30f; int i1 = (i0 == 0) ? 1 : 0;
#pragma unroll
            for (int e = 0; e < 8; ++e) if (e != i0) { float bv = sc[e] + bias[e]; if (bv > b1v) { b1v = bv; i1 = e; } }
            float v0 = -1e30f; int k0i = 0;
#pragma unroll
            for (int e = 0; e < 8; ++e) if (sc[e] > v0) { v0 = sc[e]; k0i = e; }
            float v1 = -1e30f;
#pragma unroll
            for (int e = 0; e < 8; ++e) if (e != k0i && sc[e] > v1) v1 = sc[e];
            float p0 = 1.f / (1.f + __expf(-v0));
            float p1 = 1.f / (1.f + __expf(-v1));
            float inv = 1.f / (p0 + p1);
            int ai = (wave * 8 + it) * 2;
            le[ai] = i0;     lg[ai] = p0 * inv;
            le[ai + 1] = i1; lg[ai + 1] = p1 * inv;
        }
    }
    __syncthreads();
    if (tid < 64) lpos[tid] = atomicAdd(&lcnt[le[tid]], 1);
    __syncthreads();
    if (tid < 8) gbase[tid] = atomicAdd(&cnt[tid * 32], lcnt[tid]);
    __syncthreads();
    if (tid < 64) {
        int e = le[tid];
        int dst = gbase[e] + lpos[tid];
        int t = blockIdx.x * 32 + (tid >> 1);
        tok[(size_t)e * Tn + dst] = t;
        slotp[t * 2 + (tid & 1)] = (e << 16) | dst;
        pg[t * 2 + (tid & 1)] = lg[tid];
    }
}

// ---------- scan ----------
__global__ void scan_kernel(const int* cnt, int* off, int* cntc) {
    if (threadIdx.x == 0 && blockIdx.x == 0) {
        int s = 0;
        for (int e = 0; e < 8; ++e) { int c = cnt[e * 32]; cntc[e] = c; off[e] = s; s += c; }
        off[8] = s;
        cntc[8] = Tn;
    }
}

// ---------- stage1: GEMM vs 32-col-interleaved w13 (N=2048), 32x32x16 MFMA ----------
// 1-D grid, 9216 blocks. XCD-pinned decode: xcd = b&7.
//   slot<1024: routed expert e=xcd, x=slot>>4 (0..63), y=slot&15.
//   else: shared e=8, s=slot-1024 (0..127), x=xcd*8+(s>>4), y=s&15.
__global__ __launch_bounds__(256, 2) void stage1_kernel(
        const ushort* __restrict__ xb, const ushort* __restrict__ w13t,
        const int* __restrict__ tok, const int* __restrict__ cntc,
        const int* __restrict__ off, ushort* __restrict__ Hbuf) {
    int b = blockIdx.x;
    int xcd = b & 7, slot = b >> 3;
    int e, xblk, yblk;
    if (slot < 1024) { e = xcd; xblk = slot >> 4; yblk = slot & 15; }
    else { int s = slot - 1024; e = 8; xblk = (xcd << 3) + (s >> 4); yblk = s & 15; }
    int cn = cntc[e];
    int m0 = xblk * 128;
    if (m0 >= cn) return;
    int n0 = yblk * 128;
    const ushort* we = w13t + (size_t)e * 2 * Hh * Dd;

    __shared__ ushort As[128 * 64];
    __shared__ ushort Bs[128 * 64];
    __shared__ int toks[128];

    int tid = threadIdx.x;
    if (tid < 128) {
        int sl2 = m0 + tid;
        int sl = sl2 < cn ? sl2 : cn - 1;
        toks[tid] = (e == 8) ? sl : tok[(size_t)e * Tn + sl];
    }
    __syncthreads();

    int lane = tid & 63, wave = tid >> 6;
    int wm = (wave & 1) * 64, wn = (wave >> 1) * 64;
    int l31 = lane & 31, lk = lane >> 5;
    int lr = lane >> 3;                 // row within 8-row chunk (staging)
    int lcx = ((lane & 7) ^ lr) * 8;    // swizzled logical k-offset (shorts)

    f32x16 acc[2][2];
#pragma unroll
    for (int a = 0; a < 2; ++a)
#pragma unroll
        for (int b2 = 0; b2 < 2; ++b2) acc[a][b2] = (f32x16)(0.f);

    for (int kb = 0; kb < Dd; kb += 64) {
#pragma unroll
        for (int i = 0; i < 4; ++i) {
            int cid = wave * 4 + i;
            const ushort* g = xb + (size_t)toks[cid * 8 + lr] * Dd + kb + lcx;
            __builtin_amdgcn_global_load_lds((const AS1 void*)g, (AS3 void*)(As + cid * 512), 16, 0, 0);
        }
#pragma unroll
        for (int i = 0; i < 4; ++i) {
            int cid = wave * 4 + i;
            const ushort* g = we + (size_t)(n0 + cid * 8 + lr) * Dd + kb + lcx;
            __builtin_amdgcn_global_load_lds((const AS1 void*)g, (AS3 void*)(Bs + cid * 512), 16, 0, 0);
        }
        __syncthreads();
#pragma unroll
        for (int ks = 0; ks < 4; ++ks) {          // 4 k-slices of 16
            int px = ((ks * 2 + lk) ^ (l31 & 7)) * 8;   // swizzled 16B chunk
            short8 a[2], b2[2];
#pragma unroll
            for (int mi = 0; mi < 2; ++mi)
                a[mi] = *(const short8*)&As[(wm + mi * 32 + l31) * 64 + px];
#pragma unroll
            for (int ni = 0; ni < 2; ++ni)
                b2[ni] = *(const short8*)&Bs[(wn + ni * 32 + l31) * 64 + px];
#pragma unroll
            for (int mi = 0; mi < 2; ++mi)
#pragma unroll
                for (int ni = 0; ni < 2; ++ni)
                    acc[mi][ni] = __builtin_amdgcn_mfma_f32_32x32x16_bf16(a[mi], b2[ni], acc[mi][ni], 0, 0, 0);
        }
        __syncthreads();
    }

    int oe = off[e];
    int hcol = ((n0 + wn) >> 1) + l31;  // acc col-tile 0 = h1(fam0), tile 1 = h3(fam1), same h
#pragma unroll
    for (int mi = 0; mi < 2; ++mi)
#pragma unroll
        for (int r = 0; r < 16; ++r) {
            int row = wm + mi * 32 + (r & 3) + 8 * (r >> 2) + 4 * lk;   // C layout 32x32
            int sl2 = m0 + row;
            if (sl2 < cn) {
                float h1 = acc[mi][0][r], h3 = acc[mi][1][r];
                float s = h1 * __builtin_amdgcn_rcpf(1.f + __expf(-h1));
                Hbuf[(size_t)(oe + sl2) * Hh + hcol] = f2bf(s * h3);
            }
        }
}

// ---------- stage2: Yc[slot] = Hrow @ W2, tile 128x128, BK=64, 32x32x16 MFMA ----------
// 1-D grid, 2304 blocks. XCD-pinned decode: xcd = b&7.
//   slot<256: routed e=xcd, x=slot>>2 (0..63), y=slot&3.
//   else: shared e=8, s=slot-256 (0..31), x=xcd*8+(s>>2), y=s&3.
__global__ __launch_bounds__(256, 3) void stage2_kernel(
        const ushort* __restrict__ Hbuf, const ushort* __restrict__ w2t,
        const int* __restrict__ cntc, const int* __restrict__ off,
        ushort* __restrict__ Yc) {
    int b = blockIdx.x;
    int xcd = b & 7, slot = b >> 3;
    int e, xblk, yblk;
    if (slot < 256) { e = xcd; xblk = slot >> 2; yblk = slot & 3; }
    else { int s = slot - 256; e = 8; xblk = (xcd << 3) + (s >> 2); yblk = s & 3; }
    int cn = cntc[e];
    int m0 = xblk * 128;
    if (m0 >= cn) return;
    int n0 = yblk * 128;
    int oe = off[e];
    const ushort* w2e = w2t + (size_t)e * Dd * Hh;

    __shared__ ushort As[128 * 64];
    __shared__ ushort Bs[128 * 64];

    int tid = threadIdx.x;
    int lane = tid & 63, wave = tid >> 6;
    int wm = (wave & 1) * 64, wn = (wave >> 1) * 64;
    int l31 = lane & 31, lk = lane >> 5;
    int lr = lane >> 3;
    int lcx = ((lane & 7) ^ lr) * 8;

    f32x16 acc[2][2];
#pragma unroll
    for (int a = 0; a < 2; ++a)
#pragma unroll
        for (int b2 = 0; b2 < 2; ++b2) acc[a][b2] = (f32x16)(0.f);

    for (int kb = 0; kb < Hh; kb += 64) {
#pragma unroll
        for (int i = 0; i < 4; ++i) {
            int cid = wave * 4 + i;
            const ushort* g = Hbuf + (size_t)(oe + m0 + cid * 8 + lr) * Hh + kb + lcx;
            __builtin_amdgcn_global_load_lds((const AS1 void*)g, (AS3 void*)(As + cid * 512), 16, 0, 0);
        }
#pragma unroll
        for (int i = 0; i < 4; ++i) {
            int cid = wave * 4 + i;
            const ushort* g = w2e + (size_t)(n0 + cid * 8 + lr) * Hh + kb + lcx;
            __builtin_amdgcn_global_load_lds((const AS1 void*)g, (AS3 void*)(Bs + cid * 512), 16, 0, 0);
        }
        __syncthreads();
#pragma unroll
        for (int ks = 0; ks < 4; ++ks) {
            int px = ((ks * 2 + lk) ^ (l31 & 7)) * 8;
            short8 a[2], b2[2];
#pragma unroll
            for (int mi = 0; mi < 2; ++mi)
                a[mi] = *(const short8*)&As[(wm + mi * 32 + l31) * 64 + px];
#pragma unroll
            for (int ni = 0; ni < 2; ++ni)
                b2[ni] = *(const short8*)&Bs[(wn + ni * 32 + l31) * 64 + px];
#pragma unroll
            for (int mi = 0; mi < 2; ++mi)
#pragma unroll
                for (int ni = 0; ni < 2; ++ni)
                    acc[mi][ni] = __builtin_amdgcn_mfma_f32_32x32x16_bf16(a[mi], b2[ni], acc[mi][ni], 0, 0, 0);
        }
        __syncthreads();
    }

#pragma unroll
    for (int mi = 0; mi < 2; ++mi)
#pragma unroll
        for (int r = 0; r < 16; ++r) {
            int row = wm + mi * 32 + (r & 3) + 8 * (r >> 2) + 4 * lk;
            int sl2 = m0 + row;
            if (sl2 < cn) {
                size_t rowb = (size_t)(oe + sl2) * Dd;
#pragma unroll
                for (int ni = 0; ni < 2; ++ni)
                    Yc[rowb + n0 + wn + ni * 32 + l31] = f2bf(acc[mi][ni][r]);
            }
        }
}

// ---------- combine: out[t] = g0*Yc[s0] + g1*Yc[s1] + Yc[shared+t] ----------
__global__ __launch_bounds__(256) void combine_kernel(const ushort* __restrict__ Yc,
        const int* __restrict__ slotp, const float* __restrict__ pg,
        const int* __restrict__ off, float* __restrict__ out) {
    int g = blockIdx.x * 256 + threadIdx.x;
    int t = g >> 6;
    int c = (g & 63) * 8;
    int p0 = slotp[t * 2], p1 = slotp[t * 2 + 1];
    float g0 = pg[t * 2], g1 = pg[t * 2 + 1];
    int s0 = off[p0 >> 16] + (p0 & 0xffff);
    int s1 = off[p1 >> 16] + (p1 & 0xffff);
    int s2 = off[8] + t;
    short8 a = *(const short8*)(Yc + (size_t)s0 * Dd + c);
    short8 b = *(const short8*)(Yc + (size_t)s1 * Dd + c);
    short8 d = *(const short8*)(Yc + (size_t)s2 * Dd + c);
    float o[8];
#pragma unroll
    for (int i = 0; i < 8; ++i)
        o[i] = g0 * bf2f(a[i]) + g1 * bf2f(b[i]) + bf2f(d[i]);
    float* dst = out + (size_t)t * Dd + c;
    *(float4*)dst = (float4){o[0], o[1], o[2], o[3]};
    *(float4*)(dst + 4) = (float4){o[4], o[5], o[6], o[7]};
}

extern "C" void kernel_launch(void* const* d_in, const int* in_sizes, int n_in,
                              void* d_out, int out_size, void* d_ws, size_t ws_size,
                              hipStream_t stream) {
    (void)in_sizes; (void)n_in; (void)out_size; (void)ws_size;
    const float* x    = (const float*)d_in[0];
    const float* gw   = (const float*)d_in[1];
    const float* bias = (const float*)d_in[2];
    const float* w1   = (const float*)d_in[3];
    const float* w3   = (const float*)d_in[4];
    const float* w2   = (const float*)d_in[5];
    const float* sw1  = (const float*)d_in[6];
    const float* sw3  = (const float*)d_in[7];
    const float* sw2  = (const float*)d_in[8];
    float* out = (float*)d_out;

    char* ws = (char*)d_ws;
    ushort* xb    = (ushort*)(ws + OFF_XB);
    ushort* w13t  = (ushort*)(ws + OFF_W13T);
    ushort* w2t   = (ushort*)(ws + OFF_W2T);
    ushort* Hbuf  = (ushort*)(ws + OFF_HBUF);
    ushort* Yc    = (ushort*)(ws + OFF_YC);
    int*    tok   = (int*)(ws + OFF_TOK);
    int*    slotp = (int*)(ws + OFF_SLOTP);
    float*  pg    = (float*)(ws + OFF_PG);
    int*    cnt   = (int*)(ws + OFF_CNT);
    int*    off   = (int*)(ws + OFF_OFFS);
    int*    cntc  = off + 16;

    hipMemsetAsync(cnt, 0, 1024, stream);

    trans_kernel<<<dim3(32, 16, 27), 256, 0, stream>>>(w1, sw1, w3, sw3, w2, sw2, w13t, w2t);
    router_kernel<<<256, 256, 0, stream>>>(x, gw, bias, cnt, tok, slotp, pg, xb);
    scan_kernel<<<1, 64, 0, stream>>>(cnt, off, cntc);

    stage1_kernel<<<9216, 256, 0, stream>>>(xb, w13t, tok, cntc, off, Hbuf);
    stage2_kernel<<<2304, 256, 0, stream>>>(Hbuf, w2t, cntc, off, Yc);
    combine_kernel<<<2048, 256, 0, stream>>>(Yc, slotp, pg, off, out);
}

// Round 6
// 244.677 us; speedup vs baseline: 1.0144x; 1.0144x over previous
//
#include <hip/hip_runtime.h>
#include <hip/hip_bf16.h>

// DSMoE: B=4,S=2048 -> T=8192 tokens, D=512, H=1024, E=8 routed (top-2) + shared.
// bf16 MFMA token-gather MoE; shared expert folded in as expert 8.
// R11: R9b base (240us: XCD-pinned, 16x16 MFMA conflict-free pattern) with block
//     tile widened to 128x256 (4 waves x 64x128, acc[4][8]): MFMA per ds_read
//     1.33x -> 2.67x, turning the issue-bound inner loop MFMA-bound. LDS 49.7KB
//     = 3 blocks/CU (12 waves/CU). Staging/swizzle/pinning byte-identical.

#define Tn 8192
#define Dd 512
#define Hh 1024
#define NEx 9

typedef __attribute__((ext_vector_type(8))) short short8;
typedef __attribute__((ext_vector_type(4))) float f32x4;

#define AS1 __attribute__((address_space(1)))
#define AS3 __attribute__((address_space(3)))

#define OFF_XB    ((size_t)0)
#define OFF_W13T  (OFF_XB + (size_t)Tn * Dd * 2)
#define OFF_W2T   (OFF_W13T + (size_t)NEx * 2 * Hh * Dd * 2)
#define OFF_HBUF  (OFF_W2T + (size_t)NEx * Dd * Hh * 2)
#define OFF_TOK   (OFF_HBUF + (size_t)(3 * Tn) * Hh * 2)
#define OFF_SLOTP (OFF_TOK + (size_t)8 * Tn * 4)
#define OFF_PG    (OFF_SLOTP + (size_t)Tn * 2 * 4)
#define OFF_CNT   (OFF_PG + (size_t)Tn * 2 * 4)       // 8 counters, 128B apart
#define OFF_OFFS  (OFF_CNT + 1024)                    // off[9] then cntc[9]
#define OFF_YC    OFF_XB   // alias: Yc (25.2MB) over xb+w13t (26.9MB), dead by stage2

__device__ __forceinline__ ushort f2bf(float f) {
    unsigned int u = __float_as_uint(f);
    return (ushort)((u + 0x7fffu + ((u >> 16) & 1u)) >> 16);
}
__device__ __forceinline__ float bf2f(short s) {
    return __uint_as_float(((unsigned int)(unsigned short)s) << 16);
}

// ---------- fused transpose: 27 slices; fam 0/1 interleave into w13t ----------
// fam 0: w1, fam 1: w3 -> w13t rows n = ((h>>4)*2+fam)*16 + (h&15); fam 2: w2 plain.
__global__ __launch_bounds__(256) void trans_kernel(
        const float* __restrict__ w1, const float* __restrict__ sw1,
        const float* __restrict__ w3, const float* __restrict__ sw3,
        const float* __restrict__ w2, const float* __restrict__ sw2,
        ushort* __restrict__ w13t, ushort* __restrict__ w2t) {
    __shared__ float tile[32][33];
    int z = blockIdx.z;
    int fam = z / 9, sl = z - fam * 9;
    int tx = threadIdx.x & 31, ty = threadIdx.x >> 5;
    if (fam < 2) {
        const float* base = (fam == 0) ? ((sl < 8) ? w1 + (size_t)sl * Dd * Hh : sw1)
                                       : ((sl < 8) ? w3 + (size_t)sl * Dd * Hh : sw3);
        ushort* dst = w13t + (size_t)sl * 2 * Hh * Dd;
        int c0 = blockIdx.x * 32, r0 = blockIdx.y * 32;   // c: hidden, r: dim
#pragma unroll
        for (int k = 0; k < 4; ++k)
            tile[ty + 8 * k][tx] = base[(size_t)(r0 + ty + 8 * k) * Hh + c0 + tx];
        __syncthreads();
#pragma unroll
        for (int k = 0; k < 4; ++k) {
            int h = c0 + ty + 8 * k;
            int n = (((h >> 4) * 2 + fam) << 4) + (h & 15);
            dst[(size_t)n * Dd + r0 + tx] = f2bf(tile[tx][ty + 8 * k]);
        }
    } else {
        const float* base = (sl < 8) ? w2 + (size_t)sl * Dd * Hh : sw2;
        ushort* dst = w2t + (size_t)sl * Dd * Hh;
        int r0 = blockIdx.x * 32, c0 = blockIdx.y * 32;   // r: hidden, c: dim
#pragma unroll
        for (int k = 0; k < 4; ++k)
            tile[ty + 8 * k][tx] = base[(size_t)(r0 + ty + 8 * k) * Dd + c0 + tx];
        __syncthreads();
#pragma unroll
        for (int k = 0; k < 4; ++k)
            dst[(size_t)(c0 + ty + 8 * k) * Hh + r0 + tx] = f2bf(tile[tx][ty + 8 * k]);
    }
}

// ---------- router: 32 tokens/block, LDS-aggregated atomics; also emits xb + slot map ----------
__global__ __launch_bounds__(256) void router_kernel(const float* __restrict__ x,
                                                     const float* __restrict__ gw,
                                                     const float* __restrict__ bias,
                                                     int* __restrict__ cnt,     // padded: cnt[e*32]
                                                     int* __restrict__ tok,
                                                     int* __restrict__ slotp,
                                                     float* __restrict__ pg,
                                                     ushort* __restrict__ xb) {
    __shared__ int le[64];
    __shared__ float lg[64];
    __shared__ int lpos[64];
    __shared__ int lcnt[8];
    __shared__ int gbase[8];
    int tid = threadIdx.x, lane = tid & 63, wave = tid >> 6;
    if (tid < 8) lcnt[tid] = 0;
    __syncthreads();
    int t0 = blockIdx.x * 32 + wave * 8;
    for (int it = 0; it < 8; ++it) {
        int t = t0 + it;
        const float4* xr = (const float4*)(x + (size_t)t * Dd);
        float4 xa = xr[lane * 2], xc = xr[lane * 2 + 1];
        ushort4 o1, o2;
        o1.x = f2bf(xa.x); o1.y = f2bf(xa.y); o1.z = f2bf(xa.z); o1.w = f2bf(xa.w);
        o2.x = f2bf(xc.x); o2.y = f2bf(xc.y); o2.z = f2bf(xc.z); o2.w = f2bf(xc.w);
        *(ushort4*)(xb + (size_t)t * Dd + lane * 8) = o1;
        *(ushort4*)(xb + (size_t)t * Dd + lane * 8 + 4) = o2;
        float sc[8];
#pragma unroll
        for (int e = 0; e < 8; ++e) {
            const float4* gr = (const float4*)(gw + (size_t)e * Dd);
            float4 ga = gr[lane * 2], gc = gr[lane * 2 + 1];
            float s = xa.x * ga.x + xa.y * ga.y + xa.z * ga.z + xa.w * ga.w
                    + xc.x * gc.x + xc.y * gc.y + xc.z * gc.z + xc.w * gc.w;
#pragma unroll
            for (int o = 32; o > 0; o >>= 1) s += __shfl_xor(s, o);
            sc[e] = s;
        }
        if (lane == 0) {
            float b0 = -1e30f; int i0 = 0;
#pragma unroll
            for (int e = 0; e < 8; ++e) { float bv = sc[e] + bias[e]; if (bv > b0) { b0 = bv; i0 = e; } }
            float b1v = -1e30f; int i1 = (i0 == 0) ? 1 : 0;
#pragma unroll
            for (int e = 0; e < 8; ++e) if (e != i0) { float bv = sc[e] + bias[e]; if (bv > b1v) { b1v = bv; i1 = e; } }
            float v0 = -1e30f; int k0i = 0;
#pragma unroll
            for (int e = 0; e < 8; ++e) if (sc[e] > v0) { v0 = sc[e]; k0i = e; }
            float v1 = -1e30f;
#pragma unroll
            for (int e = 0; e < 8; ++e) if (e != k0i && sc[e] > v1) v1 = sc[e];
            float p0 = 1.f / (1.f + __expf(-v0));
            float p1 = 1.f / (1.f + __expf(-v1));
            float inv = 1.f / (p0 + p1);
            int ai = (wave * 8 + it) * 2;
            le[ai] = i0;     lg[ai] = p0 * inv;
            le[ai + 1] = i1; lg[ai + 1] = p1 * inv;
        }
    }
    __syncthreads();
    if (tid < 64) lpos[tid] = atomicAdd(&lcnt[le[tid]], 1);
    __syncthreads();
    if (tid < 8) gbase[tid] = atomicAdd(&cnt[tid * 32], lcnt[tid]);
    __syncthreads();
    if (tid < 64) {
        int e = le[tid];
        int dst = gbase[e] + lpos[tid];
        int t = blockIdx.x * 32 + (tid >> 1);
        tok[(size_t)e * Tn + dst] = t;
        slotp[t * 2 + (tid & 1)] = (e << 16) | dst;
        pg[t * 2 + (tid & 1)] = lg[tid];
    }
}

// ---------- scan ----------
__global__ void scan_kernel(const int* cnt, int* off, int* cntc) {
    if (threadIdx.x == 0 && blockIdx.x == 0) {
        int s = 0;
        for (int e = 0; e < 8; ++e) { int c = cnt[e * 32]; cntc[e] = c; off[e] = s; s += c; }
        off[8] = s;
        cntc[8] = Tn;
    }
}

// ---------- stage1: GEMM vs interleaved w13 (N=2048), tile 128x256, wave 64x128 ----------
// 1-D grid, 4608 blocks. XCD-pinned decode: xcd = b&7.
//   slot<512: routed expert e=xcd, x=slot>>3 (0..63), y=slot&7.
//   else: shared e=8, s=slot-512 (0..63), x=xcd*8+(s>>3), y=s&7.
__global__ __launch_bounds__(256, 2) void stage1_kernel(
        const ushort* __restrict__ xb, const ushort* __restrict__ w13t,
        const int* __restrict__ tok, const int* __restrict__ cntc,
        const int* __restrict__ off, ushort* __restrict__ Hbuf) {
    int b = blockIdx.x;
    int xcd = b & 7, slot = b >> 3;
    int e, xblk, yblk;
    if (slot < 512) { e = xcd; xblk = slot >> 3; yblk = slot & 7; }
    else { int s = slot - 512; e = 8; xblk = (xcd << 3) + (s >> 3); yblk = s & 7; }
    int cn = cntc[e];
    int m0 = xblk * 128;
    if (m0 >= cn) return;
    int n0 = yblk * 256;
    const ushort* we = w13t + (size_t)e * 2 * Hh * Dd;

    __shared__ ushort As[128 * 64];
    __shared__ ushort Bs[256 * 64];
    __shared__ int toks[128];

    int tid = threadIdx.x;
    if (tid < 128) {
        int sl2 = m0 + tid;
        int sl = sl2 < cn ? sl2 : cn - 1;
        toks[tid] = (e == 8) ? sl : tok[(size_t)e * Tn + sl];
    }
    __syncthreads();

    int lane = tid & 63, wave = tid >> 6;
    int wm = (wave & 1) * 64, wn = (wave >> 1) * 128;
    int col15 = lane & 15, quad = lane >> 4;
    int lr = lane >> 3;                 // row within 8-row chunk (staging)
    int lcx = ((lane & 7) ^ lr) * 8;    // swizzled logical k-offset (shorts)

    f32x4 acc[4][8];
#pragma unroll
    for (int a = 0; a < 4; ++a)
#pragma unroll
        for (int b2 = 0; b2 < 8; ++b2) acc[a][b2] = (f32x4){0.f, 0.f, 0.f, 0.f};

    for (int kb = 0; kb < Dd; kb += 64) {
#pragma unroll
        for (int i = 0; i < 4; ++i) {
            int cid = wave * 4 + i;
            const ushort* g = xb + (size_t)toks[cid * 8 + lr] * Dd + kb + lcx;
            __builtin_amdgcn_global_load_lds((const AS1 void*)g, (AS3 void*)(As + cid * 512), 16, 0, 0);
        }
#pragma unroll
        for (int i = 0; i < 8; ++i) {
            int cid = wave * 8 + i;
            const ushort* g = we + (size_t)(n0 + cid * 8 + lr) * Dd + kb + lcx;
            __builtin_amdgcn_global_load_lds((const AS1 void*)g, (AS3 void*)(Bs + cid * 512), 16, 0, 0);
        }
        __syncthreads();
#pragma unroll
        for (int ks = 0; ks < 2; ++ks) {
            int px = ((ks * 4 + quad) ^ (col15 & 7)) * 8;   // swizzled k-offset (shorts)
            short8 a[4], b2[8];
#pragma unroll
            for (int mi = 0; mi < 4; ++mi)
                a[mi] = *(const short8*)&As[(wm + mi * 16 + col15) * 64 + px];
#pragma unroll
            for (int ni = 0; ni < 8; ++ni)
                b2[ni] = *(const short8*)&Bs[(wn + ni * 16 + col15) * 64 + px];
#pragma unroll
            for (int mi = 0; mi < 4; ++mi)
#pragma unroll
                for (int ni = 0; ni < 8; ++ni)
                    acc[mi][ni] = __builtin_amdgcn_mfma_f32_16x16x32_bf16(a[mi], b2[ni], acc[mi][ni], 0, 0, 0);
        }
        __syncthreads();
    }

    int oe = off[e];
    int hbase = (n0 + wn) >> 1;         // col pairs (2np,2np+1) -> h block np
#pragma unroll
    for (int mi = 0; mi < 4; ++mi)
#pragma unroll
        for (int r = 0; r < 4; ++r) {
            int sl2 = m0 + wm + mi * 16 + quad * 4 + r;   // C layout: row = quad*4+reg
            if (sl2 < cn) {
                size_t rowb = (size_t)(oe + sl2) * Hh;
#pragma unroll
                for (int np = 0; np < 4; ++np) {
                    float h1 = acc[mi][np * 2][r], h3 = acc[mi][np * 2 + 1][r];
                    float s = h1 / (1.f + __expf(-h1));
                    Hbuf[rowb + hbase + np * 16 + col15] = f2bf(s * h3);
                }
            }
        }
}

// ---------- stage2: Yc[slot] = Hrow @ W2, tile 128x256, wave 64x128, BK=64 ----------
// 1-D grid, 1152 blocks. XCD-pinned decode: xcd = b&7.
//   slot<128: routed e=xcd, x=slot>>1 (0..63), y=slot&1.
//   else: shared e=8, s=slot-128 (0..15), x=xcd*8+(s>>1), y=s&1.
__global__ __launch_bounds__(256, 2) void stage2_kernel(
        const ushort* __restrict__ Hbuf, const ushort* __restrict__ w2t,
        const int* __restrict__ cntc, const int* __restrict__ off,
        ushort* __restrict__ Yc) {
    int b = blockIdx.x;
    int xcd = b & 7, slot = b >> 3;
    int e, xblk, yblk;
    if (slot < 128) { e = xcd; xblk = slot >> 1; yblk = slot & 1; }
    else { int s = slot - 128; e = 8; xblk = (xcd << 3) + (s >> 1); yblk = s & 1; }
    int cn = cntc[e];
    int m0 = xblk * 128;
    if (m0 >= cn) return;
    int n0 = yblk * 256;
    int oe = off[e];
    const ushort* w2e = w2t + (size_t)e * Dd * Hh;

    __shared__ ushort As[128 * 64];
    __shared__ ushort Bs[256 * 64];

    int tid = threadIdx.x;
    int lane = tid & 63, wave = tid >> 6;
    int wm = (wave & 1) * 64, wn = (wave >> 1) * 128;
    int col15 = lane & 15, quad = lane >> 4;
    int lr = lane >> 3;
    int lcx = ((lane & 7) ^ lr) * 8;

    f32x4 acc[4][8];
#pragma unroll
    for (int a = 0; a < 4; ++a)
#pragma unroll
        for (int b2 = 0; b2 < 8; ++b2) acc[a][b2] = (f32x4){0.f, 0.f, 0.f, 0.f};

    for (int kb = 0; kb < Hh; kb += 64) {
#pragma unroll
        for (int i = 0; i < 4; ++i) {
            int cid = wave * 4 + i;
            const ushort* g = Hbuf + (size_t)(oe + m0 + cid * 8 + lr) * Hh + kb + lcx;
            __builtin_amdgcn_global_load_lds((const AS1 void*)g, (AS3 void*)(As + cid * 512), 16, 0, 0);
        }
#pragma unroll
        for (int i = 0; i < 8; ++i) {
            int cid = wave * 8 + i;
            const ushort* g = w2e + (size_t)(n0 + cid * 8 + lr) * Hh + kb + lcx;
            __builtin_amdgcn_global_load_lds((const AS1 void*)g, (AS3 void*)(Bs + cid * 512), 16, 0, 0);
        }
        __syncthreads();
#pragma unroll
        for (int ks = 0; ks < 2; ++ks) {
            int px = ((ks * 4 + quad) ^ (col15 & 7)) * 8;
            short8 a[4], b2[8];
#pragma unroll
            for (int mi = 0; mi < 4; ++mi)
                a[mi] = *(const short8*)&As[(wm + mi * 16 + col15) * 64 + px];
#pragma unroll
            for (int ni = 0; ni < 8; ++ni)
                b2[ni] = *(const short8*)&Bs[(wn + ni * 16 + col15) * 64 + px];
#pragma unroll
            for (int mi = 0; mi < 4; ++mi)
#pragma unroll
                for (int ni = 0; ni < 8; ++ni)
                    acc[mi][ni] = __builtin_amdgcn_mfma_f32_16x16x32_bf16(a[mi], b2[ni], acc[mi][ni], 0, 0, 0);
        }
        __syncthreads();
    }

#pragma unroll
    for (int mi = 0; mi < 4; ++mi)
#pragma unroll
        for (int r = 0; r < 4; ++r) {
            int sl2 = m0 + wm + mi * 16 + quad * 4 + r;
            if (sl2 < cn) {
                size_t rowb = (size_t)(oe + sl2) * Dd;
#pragma unroll
                for (int ni = 0; ni < 8; ++ni)
                    Yc[rowb + n0 + wn + ni * 16 + col15] = f2bf(acc[mi][ni][r]);
            }
        }
}

// ---------- combine: out[t] = g0*Yc[s0] + g1*Yc[s1] + Yc[shared+t] ----------
__global__ __launch_bounds__(256) void combine_kernel(const ushort* __restrict__ Yc,
        const int* __restrict__ slotp, const float* __restrict__ pg,
        const int* __restrict__ off, float* __restrict__ out) {
    int g = blockIdx.x * 256 + threadIdx.x;
    int t = g >> 6;
    int c = (g & 63) * 8;
    int p0 = slotp[t * 2], p1 = slotp[t * 2 + 1];
    float g0 = pg[t * 2], g1 = pg[t * 2 + 1];
    int s0 = off[p0 >> 16] + (p0 & 0xffff);
    int s1 = off[p1 >> 16] + (p1 & 0xffff);
    int s2 = off[8] + t;
    short8 a = *(const short8*)(Yc + (size_t)s0 * Dd + c);
    short8 b = *(const short8*)(Yc + (size_t)s1 * Dd + c);
    short8 d = *(const short8*)(Yc + (size_t)s2 * Dd + c);
    float o[8];
#pragma unroll
    for (int i = 0; i < 8; ++i)
        o[i] = g0 * bf2f(a[i]) + g1 * bf2f(b[i]) + bf2f(d[i]);
    float* dst = out + (size_t)t * Dd + c;
    *(float4*)dst = (float4){o[0], o[1], o[2], o[3]};
    *(float4*)(dst + 4) = (float4){o[4], o[5], o[6], o[7]};
}

extern "C" void kernel_launch(void* const* d_in, const int* in_sizes, int n_in,
                              void* d_out, int out_size, void* d_ws, size_t ws_size,
                              hipStream_t stream) {
    (void)in_sizes; (void)n_in; (void)out_size; (void)ws_size;
    const float* x    = (const float*)d_in[0];
    const float* gw   = (const float*)d_in[1];
    const float* bias = (const float*)d_in[2];
    const float* w1   = (const float*)d_in[3];
    const float* w3   = (const float*)d_in[4];
    const float* w2   = (const float*)d_in[5];
    const float* sw1  = (const float*)d_in[6];
    const float* sw3  = (const float*)d_in[7];
    const float* sw2  = (const float*)d_in[8];
    float* out = (float*)d_out;

    char* ws = (char*)d_ws;
    ushort* xb    = (ushort*)(ws + OFF_XB);
    ushort* w13t  = (ushort*)(ws + OFF_W13T);
    ushort* w2t   = (ushort*)(ws + OFF_W2T);
    ushort* Hbuf  = (ushort*)(ws + OFF_HBUF);
    ushort* Yc    = (ushort*)(ws + OFF_YC);
    int*    tok   = (int*)(ws + OFF_TOK);
    int*    slotp = (int*)(ws + OFF_SLOTP);
    float*  pg    = (float*)(ws + OFF_PG);
    int*    cnt   = (int*)(ws + OFF_CNT);
    int*    off   = (int*)(ws + OFF_OFFS);
    int*    cntc  = off + 16;

    hipMemsetAsync(cnt, 0, 1024, stream);

    trans_kernel<<<dim3(32, 16, 27), 256, 0, stream>>>(w1, sw1, w3, sw3, w2, sw2, w13t, w2t);
    router_kernel<<<256, 256, 0, stream>>>(x, gw, bias, cnt, tok, slotp, pg, xb);
    scan_kernel<<<1, 64, 0, stream>>>(cnt, off, cntc);

    stage1_kernel<<<4608, 256, 0, stream>>>(xb, w13t, tok, cntc, off, Hbuf);
    stage2_kernel<<<1152, 256, 0, stream>>>(Hbuf, w2t, cntc, off, Yc);
    combine_kernel<<<2048, 256, 0, stream>>>(Yc, slotp, pg, off, out);
}

// Round 7
// 239.919 us; speedup vs baseline: 1.0345x; 1.0198x over previous
//
#include <hip/hip_runtime.h>
#include <hip/hip_bf16.h>

// DSMoE: B=4,S=2048 -> T=8192 tokens, D=512, H=1024, E=8 routed (top-2) + shared.
// bf16 MFMA token-gather MoE; shared expert folded in as expert 8.
// R12: R9b geometry frozen (128x128, XCD-pinned, 240us). Changes:
//  (a) stage1/stage2 address diet: toks -> regs once, global base ptrs hoisted,
//      K-loop fully unrolled so kb folds into the 13-bit global offset field.
//      Kills the per-step ds_read of toks[] + 64-bit address rebuilds.
//  (b) trans+router+scan fused into one preproc kernel (6 -> 4 launches);
//      scan runs in the last-done router block via device-scope atomics.

#define Tn 8192
#define Dd 512
#define Hh 1024
#define NEx 9

typedef __attribute__((ext_vector_type(8))) short short8;
typedef __attribute__((ext_vector_type(4))) float f32x4;

#define AS1 __attribute__((address_space(1)))
#define AS3 __attribute__((address_space(3)))

#define OFF_XB    ((size_t)0)
#define OFF_W13T  (OFF_XB + (size_t)Tn * Dd * 2)
#define OFF_W2T   (OFF_W13T + (size_t)NEx * 2 * Hh * Dd * 2)
#define OFF_HBUF  (OFF_W2T + (size_t)NEx * Dd * Hh * 2)
#define OFF_TOK   (OFF_HBUF + (size_t)(3 * Tn) * Hh * 2)
#define OFF_SLOTP (OFF_TOK + (size_t)8 * Tn * 4)
#define OFF_PG    (OFF_SLOTP + (size_t)Tn * 2 * 4)
#define OFF_CNT   (OFF_PG + (size_t)Tn * 2 * 4)       // 8 counters, 128B apart; cnt[16]=done ctr
#define OFF_OFFS  (OFF_CNT + 1024)                    // off[9] then cntc[9]
#define OFF_YC    OFF_XB   // alias: Yc (25.2MB) over xb+w13t (26.9MB), dead by stage2

__device__ __forceinline__ ushort f2bf(float f) {
    unsigned int u = __float_as_uint(f);
    return (ushort)((u + 0x7fffu + ((u >> 16) & 1u)) >> 16);
}
__device__ __forceinline__ float bf2f(short s) {
    return __uint_as_float(((unsigned int)(unsigned short)s) << 16);
}

// ---------- preproc: router (blocks 0..255) + weight transpose (blocks 256..14079) ----------
// trans: 27 slices; fam 0: w1, fam 1: w3 -> w13t rows n = ((h>>4)*2+fam)*16+(h&15); fam 2: w2.
// router: 32 tokens/block, LDS-aggregated atomics; emits xb + slot map.
// scan: last router block to finish (device-scope done counter) computes off/cntc.
__global__ __launch_bounds__(256) void preproc_kernel(
        const float* __restrict__ x, const float* __restrict__ gw,
        const float* __restrict__ bias,
        const float* __restrict__ w1, const float* __restrict__ sw1,
        const float* __restrict__ w3, const float* __restrict__ sw3,
        const float* __restrict__ w2, const float* __restrict__ sw2,
        ushort* __restrict__ w13t, ushort* __restrict__ w2t,
        int* __restrict__ cnt, int* __restrict__ tok,
        int* __restrict__ slotp, float* __restrict__ pg,
        ushort* __restrict__ xb, int* __restrict__ off, int* __restrict__ cntc) {
    __shared__ float tile[32][33];
    __shared__ int le[64];
    __shared__ float lg[64];
    __shared__ int lpos[64];
    __shared__ int lcnt[8];
    __shared__ int gbase[8];
    int bb = blockIdx.x;
    int tid = threadIdx.x;

    if (bb >= 256) {                       // ---- transpose path ----
        int tb = bb - 256;
        int z = tb >> 9;
        int fam = z / 9, sl = z - fam * 9;
        int bxx = tb & 31, byy = (tb >> 5) & 15;
        int tx = tid & 31, ty = tid >> 5;
        if (fam < 2) {
            const float* base = (fam == 0) ? ((sl < 8) ? w1 + (size_t)sl * Dd * Hh : sw1)
                                           : ((sl < 8) ? w3 + (size_t)sl * Dd * Hh : sw3);
            ushort* dst = w13t + (size_t)sl * 2 * Hh * Dd;
            int c0 = bxx * 32, r0 = byy * 32;   // c: hidden, r: dim
#pragma unroll
            for (int k = 0; k < 4; ++k)
                tile[ty + 8 * k][tx] = base[(size_t)(r0 + ty + 8 * k) * Hh + c0 + tx];
            __syncthreads();
#pragma unroll
            for (int k = 0; k < 4; ++k) {
                int h = c0 + ty + 8 * k;
                int n = (((h >> 4) * 2 + fam) << 4) + (h & 15);
                dst[(size_t)n * Dd + r0 + tx] = f2bf(tile[tx][ty + 8 * k]);
            }
        } else {
            const float* base = (sl < 8) ? w2 + (size_t)sl * Dd * Hh : sw2;
            ushort* dst = w2t + (size_t)sl * Dd * Hh;
            int r0 = bxx * 32, c0 = byy * 32;   // r: hidden, c: dim
#pragma unroll
            for (int k = 0; k < 4; ++k)
                tile[ty + 8 * k][tx] = base[(size_t)(r0 + ty + 8 * k) * Dd + c0 + tx];
            __syncthreads();
#pragma unroll
            for (int k = 0; k < 4; ++k)
                dst[(size_t)(c0 + ty + 8 * k) * Hh + r0 + tx] = f2bf(tile[tx][ty + 8 * k]);
        }
        return;
    }

    // ---- router path ----
    int lane = tid & 63, wave = tid >> 6;
    if (tid < 8) lcnt[tid] = 0;
    __syncthreads();
    int t0 = bb * 32 + wave * 8;
    for (int it = 0; it < 8; ++it) {
        int t = t0 + it;
        const float4* xr = (const float4*)(x + (size_t)t * Dd);
        float4 xa = xr[lane * 2], xc = xr[lane * 2 + 1];
        ushort4 o1, o2;
        o1.x = f2bf(xa.x); o1.y = f2bf(xa.y); o1.z = f2bf(xa.z); o1.w = f2bf(xa.w);
        o2.x = f2bf(xc.x); o2.y = f2bf(xc.y); o2.z = f2bf(xc.z); o2.w = f2bf(xc.w);
        *(ushort4*)(xb + (size_t)t * Dd + lane * 8) = o1;
        *(ushort4*)(xb + (size_t)t * Dd + lane * 8 + 4) = o2;
        float sc[8];
#pragma unroll
        for (int e = 0; e < 8; ++e) {
            const float4* gr = (const float4*)(gw + (size_t)e * Dd);
            float4 ga = gr[lane * 2], gc = gr[lane * 2 + 1];
            float s = xa.x * ga.x + xa.y * ga.y + xa.z * ga.z + xa.w * ga.w
                    + xc.x * gc.x + xc.y * gc.y + xc.z * gc.z + xc.w * gc.w;
#pragma unroll
            for (int o = 32; o > 0; o >>= 1) s += __shfl_xor(s, o);
            sc[e] = s;
        }
        if (lane == 0) {
            float b0 = -1e30f; int i0 = 0;
#pragma unroll
            for (int e = 0; e < 8; ++e) { float bv = sc[e] + bias[e]; if (bv > b0) { b0 = bv; i0 = e; } }
            float b1v = -1e30f; int i1 = (i0 == 0) ? 1 : 0;
#pragma unroll
            for (int e = 0; e < 8; ++e) if (e != i0) { float bv = sc[e] + bias[e]; if (bv > b1v) { b1v = bv; i1 = e; } }
            float v0 = -1e30f; int k0i = 0;
#pragma unroll
            for (int e = 0; e < 8; ++e) if (sc[e] > v0) { v0 = sc[e]; k0i = e; }
            float v1 = -1e30f;
#pragma unroll
            for (int e = 0; e < 8; ++e) if (e != k0i && sc[e] > v1) v1 = sc[e];
            float p0 = 1.f / (1.f + __expf(-v0));
            float p1 = 1.f / (1.f + __expf(-v1));
            float inv = 1.f / (p0 + p1);
            int ai = (wave * 8 + it) * 2;
            le[ai] = i0;     lg[ai] = p0 * inv;
            le[ai + 1] = i1; lg[ai + 1] = p1 * inv;
        }
    }
    __syncthreads();
    if (tid < 64) lpos[tid] = atomicAdd(&lcnt[le[tid]], 1);
    __syncthreads();
    if (tid < 8) gbase[tid] = atomicAdd(&cnt[tid * 32], lcnt[tid]);
    __syncthreads();
    if (tid < 64) {
        int e = le[tid];
        int dst = gbase[e] + lpos[tid];
        int t = bb * 32 + (tid >> 1);
        tok[(size_t)e * Tn + dst] = t;
        slotp[t * 2 + (tid & 1)] = (e << 16) | dst;
        pg[t * 2 + (tid & 1)] = lg[tid];
    }
    __syncthreads();
    if (tid == 0) {
        __threadfence();
        if (atomicAdd(&cnt[16], 1) == 255) {   // last router block: do the scan
            int s = 0;
            for (int e = 0; e < 8; ++e) {
                int c = atomicAdd(&cnt[e * 32], 0);   // atomic read = coherent
                cntc[e] = c; off[e] = s; s += c;
            }
            off[8] = s;
            cntc[8] = Tn;
        }
    }
}

// ---------- stage1: GEMM vs interleaved w13 (N=2048), tile 128x128, BK=64 ----------
// 1-D grid, 9216 blocks. XCD-pinned decode: xcd = b&7.
//   slot<1024: routed expert e=xcd, x=slot>>4 (0..63), y=slot&15.
//   else: shared e=8, s=slot-1024 (0..127), x=xcd*8+(s>>4), y=s&15.
// Address diet: toks->regs, base ptrs hoisted, K-loop fully unrolled.
__global__ __launch_bounds__(256, 2) void stage1_kernel(
        const ushort* __restrict__ xb, const ushort* __restrict__ w13t,
        const int* __restrict__ tok, const int* __restrict__ cntc,
        const int* __restrict__ off, ushort* __restrict__ Hbuf) {
    int b = blockIdx.x;
    int xcd = b & 7, slot = b >> 3;
    int e, xblk, yblk;
    if (slot < 1024) { e = xcd; xblk = slot >> 4; yblk = slot & 15; }
    else { int s = slot - 1024; e = 8; xblk = (xcd << 3) + (s >> 4); yblk = s & 15; }
    int cn = cntc[e];
    int m0 = xblk * 128;
    if (m0 >= cn) return;
    int n0 = yblk * 128;
    const ushort* we = w13t + (size_t)e * 2 * Hh * Dd;

    __shared__ ushort As[128 * 64];
    __shared__ ushort Bs[128 * 64];
    __shared__ int toks[128];

    int tid = threadIdx.x;
    if (tid < 128) {
        int sl2 = m0 + tid;
        int sl = sl2 < cn ? sl2 : cn - 1;
        toks[tid] = (e == 8) ? sl : tok[(size_t)e * Tn + sl];
    }
    __syncthreads();

    int lane = tid & 63, wave = tid >> 6;
    int wm = (wave & 1) * 64, wn = (wave >> 1) * 64;
    int col15 = lane & 15, quad = lane >> 4;
    int lr = lane >> 3;                 // row within 8-row chunk (staging)
    int lcx = ((lane & 7) ^ lr) * 8;    // swizzled logical k-offset (shorts)

    const ushort* gA[4];
    const ushort* gB[4];
#pragma unroll
    for (int i = 0; i < 4; ++i) {
        int cid = wave * 4 + i;
        gA[i] = xb + (size_t)toks[cid * 8 + lr] * Dd + lcx;
        gB[i] = we + (size_t)(n0 + cid * 8 + lr) * Dd + lcx;
    }

    f32x4 acc[4][4];
#pragma unroll
    for (int a = 0; a < 4; ++a)
#pragma unroll
        for (int b2 = 0; b2 < 4; ++b2) acc[a][b2] = (f32x4){0.f, 0.f, 0.f, 0.f};

#pragma unroll
    for (int kb = 0; kb < Dd; kb += 64) {
#pragma unroll
        for (int i = 0; i < 4; ++i)
            __builtin_amdgcn_global_load_lds((const AS1 void*)(gA[i] + kb), (AS3 void*)(As + (wave * 4 + i) * 512), 16, 0, 0);
#pragma unroll
        for (int i = 0; i < 4; ++i)
            __builtin_amdgcn_global_load_lds((const AS1 void*)(gB[i] + kb), (AS3 void*)(Bs + (wave * 4 + i) * 512), 16, 0, 0);
        __syncthreads();
#pragma unroll
        for (int ks = 0; ks < 2; ++ks) {
            int px = ((ks * 4 + quad) ^ (col15 & 7)) * 8;   // swizzled k-offset (shorts)
            short8 a[4], b2[4];
#pragma unroll
            for (int mi = 0; mi < 4; ++mi)
                a[mi] = *(const short8*)&As[(wm + mi * 16 + col15) * 64 + px];
#pragma unroll
            for (int ni = 0; ni < 4; ++ni)
                b2[ni] = *(const short8*)&Bs[(wn + ni * 16 + col15) * 64 + px];
#pragma unroll
            for (int mi = 0; mi < 4; ++mi)
#pragma unroll
                for (int ni = 0; ni < 4; ++ni)
                    acc[mi][ni] = __builtin_amdgcn_mfma_f32_16x16x32_bf16(a[mi], b2[ni], acc[mi][ni], 0, 0, 0);
        }
        __syncthreads();
    }

    int oe = off[e];
    int hbase = (n0 + wn) >> 1;         // cols ni={0,1} -> h block 0, ni={2,3} -> h block 1
#pragma unroll
    for (int mi = 0; mi < 4; ++mi)
#pragma unroll
        for (int r = 0; r < 4; ++r) {
            int sl2 = m0 + wm + mi * 16 + quad * 4 + r;   // C layout: row = quad*4+reg
            if (sl2 < cn) {
                size_t rowb = (size_t)(oe + sl2) * Hh;
#pragma unroll
                for (int np = 0; np < 2; ++np) {
                    float h1 = acc[mi][np * 2][r], h3 = acc[mi][np * 2 + 1][r];
                    float s = h1 / (1.f + __expf(-h1));
                    Hbuf[rowb + hbase + np * 16 + col15] = f2bf(s * h3);
                }
            }
        }
}

// ---------- stage2: Yc[slot] = Hrow @ W2, tile 128x128, BK=64 ----------
// 1-D grid, 2304 blocks. XCD-pinned decode: xcd = b&7.
//   slot<256: routed e=xcd, x=slot>>2 (0..63), y=slot&3.
//   else: shared e=8, s=slot-256 (0..31), x=xcd*8+(s>>2), y=s&3.
__global__ __launch_bounds__(256, 3) void stage2_kernel(
        const ushort* __restrict__ Hbuf, const ushort* __restrict__ w2t,
        const int* __restrict__ cntc, const int* __restrict__ off,
        ushort* __restrict__ Yc) {
    int b = blockIdx.x;
    int xcd = b & 7, slot = b >> 3;
    int e, xblk, yblk;
    if (slot < 256) { e = xcd; xblk = slot >> 2; yblk = slot & 3; }
    else { int s = slot - 256; e = 8; xblk = (xcd << 3) + (s >> 2); yblk = s & 3; }
    int cn = cntc[e];
    int m0 = xblk * 128;
    if (m0 >= cn) return;
    int n0 = yblk * 128;
    int oe = off[e];
    const ushort* w2e = w2t + (size_t)e * Dd * Hh;

    __shared__ ushort As[128 * 64];
    __shared__ ushort Bs[128 * 64];

    int tid = threadIdx.x;
    int lane = tid & 63, wave = tid >> 6;
    int wm = (wave & 1) * 64, wn = (wave >> 1) * 64;
    int col15 = lane & 15, quad = lane >> 4;
    int lr = lane >> 3;
    int lcx = ((lane & 7) ^ lr) * 8;

    const ushort* gA[4];
    const ushort* gB[4];
#pragma unroll
    for (int i = 0; i < 4; ++i) {
        int cid = wave * 4 + i;
        gA[i] = Hbuf + (size_t)(oe + m0 + cid * 8 + lr) * Hh + lcx;
        gB[i] = w2e + (size_t)(n0 + cid * 8 + lr) * Hh + lcx;
    }

    f32x4 acc[4][4];
#pragma unroll
    for (int a = 0; a < 4; ++a)
#pragma unroll
        for (int b2 = 0; b2 < 4; ++b2) acc[a][b2] = (f32x4){0.f, 0.f, 0.f, 0.f};

#pragma unroll
    for (int kb = 0; kb < Hh; kb += 64) {
#pragma unroll
        for (int i = 0; i < 4; ++i)
            __builtin_amdgcn_global_load_lds((const AS1 void*)(gA[i] + kb), (AS3 void*)(As + (wave * 4 + i) * 512), 16, 0, 0);
#pragma unroll
        for (int i = 0; i < 4; ++i)
            __builtin_amdgcn_global_load_lds((const AS1 void*)(gB[i] + kb), (AS3 void*)(Bs + (wave * 4 + i) * 512), 16, 0, 0);
        __syncthreads();
#pragma unroll
        for (int ks = 0; ks < 2; ++ks) {
            int px = ((ks * 4 + quad) ^ (col15 & 7)) * 8;
            short8 a[4], b2[4];
#pragma unroll
            for (int mi = 0; mi < 4; ++mi)
                a[mi] = *(const short8*)&As[(wm + mi * 16 + col15) * 64 + px];
#pragma unroll
            for (int ni = 0; ni < 4; ++ni)
                b2[ni] = *(const short8*)&Bs[(wn + ni * 16 + col15) * 64 + px];
#pragma unroll
            for (int mi = 0; mi < 4; ++mi)
#pragma unroll
                for (int ni = 0; ni < 4; ++ni)
                    acc[mi][ni] = __builtin_amdgcn_mfma_f32_16x16x32_bf16(a[mi], b2[ni], acc[mi][ni], 0, 0, 0);
        }
        __syncthreads();
    }

#pragma unroll
    for (int mi = 0; mi < 4; ++mi)
#pragma unroll
        for (int r = 0; r < 4; ++r) {
            int sl2 = m0 + wm + mi * 16 + quad * 4 + r;
            if (sl2 < cn) {
                size_t rowb = (size_t)(oe + sl2) * Dd;
#pragma unroll
                for (int ni = 0; ni < 4; ++ni)
                    Yc[rowb + n0 + wn + ni * 16 + col15] = f2bf(acc[mi][ni][r]);
            }
        }
}

// ---------- combine: out[t] = g0*Yc[s0] + g1*Yc[s1] + Yc[shared+t] ----------
__global__ __launch_bounds__(256) void combine_kernel(const ushort* __restrict__ Yc,
        const int* __restrict__ slotp, const float* __restrict__ pg,
        const int* __restrict__ off, float* __restrict__ out) {
    int g = blockIdx.x * 256 + threadIdx.x;
    int t = g >> 6;
    int c = (g & 63) * 8;
    int p0 = slotp[t * 2], p1 = slotp[t * 2 + 1];
    float g0 = pg[t * 2], g1 = pg[t * 2 + 1];
    int s0 = off[p0 >> 16] + (p0 & 0xffff);
    int s1 = off[p1 >> 16] + (p1 & 0xffff);
    int s2 = off[8] + t;
    short8 a = *(const short8*)(Yc + (size_t)s0 * Dd + c);
    short8 b = *(const short8*)(Yc + (size_t)s1 * Dd + c);
    short8 d = *(const short8*)(Yc + (size_t)s2 * Dd + c);
    float o[8];
#pragma unroll
    for (int i = 0; i < 8; ++i)
        o[i] = g0 * bf2f(a[i]) + g1 * bf2f(b[i]) + bf2f(d[i]);
    float* dst = out + (size_t)t * Dd + c;
    *(float4*)dst = (float4){o[0], o[1], o[2], o[3]};
    *(float4*)(dst + 4) = (float4){o[4], o[5], o[6], o[7]};
}

extern "C" void kernel_launch(void* const* d_in, const int* in_sizes, int n_in,
                              void* d_out, int out_size, void* d_ws, size_t ws_size,
                              hipStream_t stream) {
    (void)in_sizes; (void)n_in; (void)out_size; (void)ws_size;
    const float* x    = (const float*)d_in[0];
    const float* gw   = (const float*)d_in[1];
    const float* bias = (const float*)d_in[2];
    const float* w1   = (const float*)d_in[3];
    const float* w3   = (const float*)d_in[4];
    const float* w2   = (const float*)d_in[5];
    const float* sw1  = (const float*)d_in[6];
    const float* sw3  = (const float*)d_in[7];
    const float* sw2  = (const float*)d_in[8];
    float* out = (float*)d_out;

    char* ws = (char*)d_ws;
    ushort* xb    = (ushort*)(ws + OFF_XB);
    ushort* w13t  = (ushort*)(ws + OFF_W13T);
    ushort* w2t   = (ushort*)(ws + OFF_W2T);
    ushort* Hbuf  = (ushort*)(ws + OFF_HBUF);
    ushort* Yc    = (ushort*)(ws + OFF_YC);
    int*    tok   = (int*)(ws + OFF_TOK);
    int*    slotp = (int*)(ws + OFF_SLOTP);
    float*  pg    = (float*)(ws + OFF_PG);
    int*    cnt   = (int*)(ws + OFF_CNT);
    int*    off   = (int*)(ws + OFF_OFFS);
    int*    cntc  = off + 16;

    hipMemsetAsync(cnt, 0, 1024, stream);

    preproc_kernel<<<14080, 256, 0, stream>>>(x, gw, bias, w1, sw1, w3, sw3, w2, sw2,
                                              w13t, w2t, cnt, tok, slotp, pg, xb, off, cntc);
    stage1_kernel<<<9216, 256, 0, stream>>>(xb, w13t, tok, cntc, off, Hbuf);
    stage2_kernel<<<2304, 256, 0, stream>>>(Hbuf, w2t, cntc, off, Yc);
    combine_kernel<<<2048, 256, 0, stream>>>(Yc, slotp, pg, off, out);
}

// Round 8
// 230.955 us; speedup vs baseline: 1.0747x; 1.0388x over previous
//
#include <hip/hip_runtime.h>
#include <hip/hip_bf16.h>

// DSMoE: B=4,S=2048 -> T=8192 tokens, D=512, H=1024, E=8 routed (top-2) + shared.
// bf16 MFMA token-gather MoE; shared expert folded in as expert 8.
// R13: R12 base (239.9us). Changes:
//  (a) preproc transpose vectorized: float4 loads + ushort4 stores (was scalar
//      4B/2B per lane -> G13 violation). Same 32x32 LDS tile, <=2-way bank alias.
//  (b) stage2 tile 128x256 (R11 evidence: -6us on stage2) + R12 address diet.
//  stage1 / router / scan-fusion / combine untouched (stage1 = 61us control).

#define Tn 8192
#define Dd 512
#define Hh 1024
#define NEx 9

typedef __attribute__((ext_vector_type(8))) short short8;
typedef __attribute__((ext_vector_type(4))) float f32x4;

#define AS1 __attribute__((address_space(1)))
#define AS3 __attribute__((address_space(3)))

#define OFF_XB    ((size_t)0)
#define OFF_W13T  (OFF_XB + (size_t)Tn * Dd * 2)
#define OFF_W2T   (OFF_W13T + (size_t)NEx * 2 * Hh * Dd * 2)
#define OFF_HBUF  (OFF_W2T + (size_t)NEx * Dd * Hh * 2)
#define OFF_TOK   (OFF_HBUF + (size_t)(3 * Tn) * Hh * 2)
#define OFF_SLOTP (OFF_TOK + (size_t)8 * Tn * 4)
#define OFF_PG    (OFF_SLOTP + (size_t)Tn * 2 * 4)
#define OFF_CNT   (OFF_PG + (size_t)Tn * 2 * 4)       // 8 counters, 128B apart; cnt[16]=done ctr
#define OFF_OFFS  (OFF_CNT + 1024)                    // off[9] then cntc[9]
#define OFF_YC    OFF_XB   // alias: Yc (25.2MB) over xb+w13t (26.9MB), dead by stage2

__device__ __forceinline__ ushort f2bf(float f) {
    unsigned int u = __float_as_uint(f);
    return (ushort)((u + 0x7fffu + ((u >> 16) & 1u)) >> 16);
}
__device__ __forceinline__ float bf2f(short s) {
    return __uint_as_float(((unsigned int)(unsigned short)s) << 16);
}

// ---------- preproc: router (blocks 0..255) + weight transpose (blocks 256..14079) ----------
// trans: 27 slices; fam 0: w1, fam 1: w3 -> w13t rows n = ((h>>4)*2+fam)*16+(h&15); fam 2: w2.
// Vectorized: one float4 load + one ushort4 store per thread per 32x32 tile.
// router: 32 tokens/block, LDS-aggregated atomics; emits xb + slot map.
// scan: last router block to finish (device-scope done counter) computes off/cntc.
__global__ __launch_bounds__(256) void preproc_kernel(
        const float* __restrict__ x, const float* __restrict__ gw,
        const float* __restrict__ bias,
        const float* __restrict__ w1, const float* __restrict__ sw1,
        const float* __restrict__ w3, const float* __restrict__ sw3,
        const float* __restrict__ w2, const float* __restrict__ sw2,
        ushort* __restrict__ w13t, ushort* __restrict__ w2t,
        int* __restrict__ cnt, int* __restrict__ tok,
        int* __restrict__ slotp, float* __restrict__ pg,
        ushort* __restrict__ xb, int* __restrict__ off, int* __restrict__ cntc) {
    __shared__ float tile[32][33];
    __shared__ int le[64];
    __shared__ float lg[64];
    __shared__ int lpos[64];
    __shared__ int lcnt[8];
    __shared__ int gbase[8];
    int bb = blockIdx.x;
    int tid = threadIdx.x;

    if (bb >= 256) {                       // ---- transpose path (vectorized) ----
        int tb = bb - 256;
        int z = tb >> 9;
        int fam = z / 9, sl = z - fam * 9;
        int bxx = tb & 31, byy = (tb >> 5) & 15;
        int t8 = tid & 7, th = tid >> 3;   // th 0..31, t8 0..7
        int tx4 = t8 * 4;
        if (fam < 2) {
            const float* base = (fam == 0) ? ((sl < 8) ? w1 + (size_t)sl * Dd * Hh : sw1)
                                           : ((sl < 8) ? w3 + (size_t)sl * Dd * Hh : sw3);
            ushort* dst = w13t + (size_t)sl * 2 * Hh * Dd;
            int c0 = bxx * 32, r0 = byy * 32;   // c: hidden, r: dim
            float4 v = *(const float4*)&base[(size_t)(r0 + th) * Hh + c0 + tx4];
            tile[th][tx4] = v.x; tile[th][tx4 + 1] = v.y;
            tile[th][tx4 + 2] = v.z; tile[th][tx4 + 3] = v.w;
            __syncthreads();
            int h = c0 + th;
            int n = (((h >> 4) * 2 + fam) << 4) + (h & 15);
            ushort4 o;
            o.x = f2bf(tile[tx4][th]);     o.y = f2bf(tile[tx4 + 1][th]);
            o.z = f2bf(tile[tx4 + 2][th]); o.w = f2bf(tile[tx4 + 3][th]);
            *(ushort4*)&dst[(size_t)n * Dd + r0 + tx4] = o;
        } else {
            const float* base = (sl < 8) ? w2 + (size_t)sl * Dd * Hh : sw2;
            ushort* dst = w2t + (size_t)sl * Dd * Hh;
            int r0 = bxx * 32, c0 = byy * 32;   // r: hidden, c: dim
            float4 v = *(const float4*)&base[(size_t)(r0 + th) * Dd + c0 + tx4];
            tile[th][tx4] = v.x; tile[th][tx4 + 1] = v.y;
            tile[th][tx4 + 2] = v.z; tile[th][tx4 + 3] = v.w;
            __syncthreads();
            int d = c0 + th;
            ushort4 o;
            o.x = f2bf(tile[tx4][th]);     o.y = f2bf(tile[tx4 + 1][th]);
            o.z = f2bf(tile[tx4 + 2][th]); o.w = f2bf(tile[tx4 + 3][th]);
            *(ushort4*)&dst[(size_t)d * Hh + r0 + tx4] = o;
        }
        return;
    }

    // ---- router path ----
    int lane = tid & 63, wave = tid >> 6;
    if (tid < 8) lcnt[tid] = 0;
    __syncthreads();
    int t0 = bb * 32 + wave * 8;
    for (int it = 0; it < 8; ++it) {
        int t = t0 + it;
        const float4* xr = (const float4*)(x + (size_t)t * Dd);
        float4 xa = xr[lane * 2], xc = xr[lane * 2 + 1];
        ushort4 o1, o2;
        o1.x = f2bf(xa.x); o1.y = f2bf(xa.y); o1.z = f2bf(xa.z); o1.w = f2bf(xa.w);
        o2.x = f2bf(xc.x); o2.y = f2bf(xc.y); o2.z = f2bf(xc.z); o2.w = f2bf(xc.w);
        *(ushort4*)(xb + (size_t)t * Dd + lane * 8) = o1;
        *(ushort4*)(xb + (size_t)t * Dd + lane * 8 + 4) = o2;
        float sc[8];
#pragma unroll
        for (int e = 0; e < 8; ++e) {
            const float4* gr = (const float4*)(gw + (size_t)e * Dd);
            float4 ga = gr[lane * 2], gc = gr[lane * 2 + 1];
            float s = xa.x * ga.x + xa.y * ga.y + xa.z * ga.z + xa.w * ga.w
                    + xc.x * gc.x + xc.y * gc.y + xc.z * gc.z + xc.w * gc.w;
#pragma unroll
            for (int o = 32; o > 0; o >>= 1) s += __shfl_xor(s, o);
            sc[e] = s;
        }
        if (lane == 0) {
            float b0 = -1e30f; int i0 = 0;
#pragma unroll
            for (int e = 0; e < 8; ++e) { float bv = sc[e] + bias[e]; if (bv > b0) { b0 = bv; i0 = e; } }
            float b1v = -1e30f; int i1 = (i0 == 0) ? 1 : 0;
#pragma unroll
            for (int e = 0; e < 8; ++e) if (e != i0) { float bv = sc[e] + bias[e]; if (bv > b1v) { b1v = bv; i1 = e; } }
            float v0 = -1e30f; int k0i = 0;
#pragma unroll
            for (int e = 0; e < 8; ++e) if (sc[e] > v0) { v0 = sc[e]; k0i = e; }
            float v1 = -1e30f;
#pragma unroll
            for (int e = 0; e < 8; ++e) if (e != k0i && sc[e] > v1) v1 = sc[e];
            float p0 = 1.f / (1.f + __expf(-v0));
            float p1 = 1.f / (1.f + __expf(-v1));
            float inv = 1.f / (p0 + p1);
            int ai = (wave * 8 + it) * 2;
            le[ai] = i0;     lg[ai] = p0 * inv;
            le[ai + 1] = i1; lg[ai + 1] = p1 * inv;
        }
    }
    __syncthreads();
    if (tid < 64) lpos[tid] = atomicAdd(&lcnt[le[tid]], 1);
    __syncthreads();
    if (tid < 8) gbase[tid] = atomicAdd(&cnt[tid * 32], lcnt[tid]);
    __syncthreads();
    if (tid < 64) {
        int e = le[tid];
        int dst = gbase[e] + lpos[tid];
        int t = bb * 32 + (tid >> 1);
        tok[(size_t)e * Tn + dst] = t;
        slotp[t * 2 + (tid & 1)] = (e << 16) | dst;
        pg[t * 2 + (tid & 1)] = lg[tid];
    }
    __syncthreads();
    if (tid == 0) {
        __threadfence();
        if (atomicAdd(&cnt[16], 1) == 255) {   // last router block: do the scan
            int s = 0;
            for (int e = 0; e < 8; ++e) {
                int c = atomicAdd(&cnt[e * 32], 0);   // atomic read = coherent
                cntc[e] = c; off[e] = s; s += c;
            }
            off[8] = s;
            cntc[8] = Tn;
        }
    }
}

// ---------- stage1: GEMM vs interleaved w13 (N=2048), tile 128x128, BK=64 ----------
// 1-D grid, 9216 blocks. XCD-pinned decode: xcd = b&7.
//   slot<1024: routed expert e=xcd, x=slot>>4 (0..63), y=slot&15.
//   else: shared e=8, s=slot-1024 (0..127), x=xcd*8+(s>>4), y=s&15.
// Address diet: toks->regs, base ptrs hoisted, K-loop fully unrolled.
__global__ __launch_bounds__(256, 2) void stage1_kernel(
        const ushort* __restrict__ xb, const ushort* __restrict__ w13t,
        const int* __restrict__ tok, const int* __restrict__ cntc,
        const int* __restrict__ off, ushort* __restrict__ Hbuf) {
    int b = blockIdx.x;
    int xcd = b & 7, slot = b >> 3;
    int e, xblk, yblk;
    if (slot < 1024) { e = xcd; xblk = slot >> 4; yblk = slot & 15; }
    else { int s = slot - 1024; e = 8; xblk = (xcd << 3) + (s >> 4); yblk = s & 15; }
    int cn = cntc[e];
    int m0 = xblk * 128;
    if (m0 >= cn) return;
    int n0 = yblk * 128;
    const ushort* we = w13t + (size_t)e * 2 * Hh * Dd;

    __shared__ ushort As[128 * 64];
    __shared__ ushort Bs[128 * 64];
    __shared__ int toks[128];

    int tid = threadIdx.x;
    if (tid < 128) {
        int sl2 = m0 + tid;
        int sl = sl2 < cn ? sl2 : cn - 1;
        toks[tid] = (e == 8) ? sl : tok[(size_t)e * Tn + sl];
    }
    __syncthreads();

    int lane = tid & 63, wave = tid >> 6;
    int wm = (wave & 1) * 64, wn = (wave >> 1) * 64;
    int col15 = lane & 15, quad = lane >> 4;
    int lr = lane >> 3;                 // row within 8-row chunk (staging)
    int lcx = ((lane & 7) ^ lr) * 8;    // swizzled logical k-offset (shorts)

    const ushort* gA[4];
    const ushort* gB[4];
#pragma unroll
    for (int i = 0; i < 4; ++i) {
        int cid = wave * 4 + i;
        gA[i] = xb + (size_t)toks[cid * 8 + lr] * Dd + lcx;
        gB[i] = we + (size_t)(n0 + cid * 8 + lr) * Dd + lcx;
    }

    f32x4 acc[4][4];
#pragma unroll
    for (int a = 0; a < 4; ++a)
#pragma unroll
        for (int b2 = 0; b2 < 4; ++b2) acc[a][b2] = (f32x4){0.f, 0.f, 0.f, 0.f};

#pragma unroll
    for (int kb = 0; kb < Dd; kb += 64) {
#pragma unroll
        for (int i = 0; i < 4; ++i)
            __builtin_amdgcn_global_load_lds((const AS1 void*)(gA[i] + kb), (AS3 void*)(As + (wave * 4 + i) * 512), 16, 0, 0);
#pragma unroll
        for (int i = 0; i < 4; ++i)
            __builtin_amdgcn_global_load_lds((const AS1 void*)(gB[i] + kb), (AS3 void*)(Bs + (wave * 4 + i) * 512), 16, 0, 0);
        __syncthreads();
#pragma unroll
        for (int ks = 0; ks < 2; ++ks) {
            int px = ((ks * 4 + quad) ^ (col15 & 7)) * 8;   // swizzled k-offset (shorts)
            short8 a[4], b2[4];
#pragma unroll
            for (int mi = 0; mi < 4; ++mi)
                a[mi] = *(const short8*)&As[(wm + mi * 16 + col15) * 64 + px];
#pragma unroll
            for (int ni = 0; ni < 4; ++ni)
                b2[ni] = *(const short8*)&Bs[(wn + ni * 16 + col15) * 64 + px];
#pragma unroll
            for (int mi = 0; mi < 4; ++mi)
#pragma unroll
                for (int ni = 0; ni < 4; ++ni)
                    acc[mi][ni] = __builtin_amdgcn_mfma_f32_16x16x32_bf16(a[mi], b2[ni], acc[mi][ni], 0, 0, 0);
        }
        __syncthreads();
    }

    int oe = off[e];
    int hbase = (n0 + wn) >> 1;         // cols ni={0,1} -> h block 0, ni={2,3} -> h block 1
#pragma unroll
    for (int mi = 0; mi < 4; ++mi)
#pragma unroll
        for (int r = 0; r < 4; ++r) {
            int sl2 = m0 + wm + mi * 16 + quad * 4 + r;   // C layout: row = quad*4+reg
            if (sl2 < cn) {
                size_t rowb = (size_t)(oe + sl2) * Hh;
#pragma unroll
                for (int np = 0; np < 2; ++np) {
                    float h1 = acc[mi][np * 2][r], h3 = acc[mi][np * 2 + 1][r];
                    float s = h1 / (1.f + __expf(-h1));
                    Hbuf[rowb + hbase + np * 16 + col15] = f2bf(s * h3);
                }
            }
        }
}

// ---------- stage2: Yc[slot] = Hrow @ W2, tile 128x256, wave 64x128, BK=64 ----------
// 1-D grid, 1152 blocks. XCD-pinned decode: xcd = b&7.
//   slot<128: routed e=xcd, x=slot>>1 (0..63), y=slot&1.
//   else: shared e=8, s=slot-128 (0..15), x=xcd*8+(s>>1), y=s&1.
// Address diet: base ptrs hoisted, K-loop fully unrolled (kb*2 <= 1984B offset).
__global__ __launch_bounds__(256, 2) void stage2_kernel(
        const ushort* __restrict__ Hbuf, const ushort* __restrict__ w2t,
        const int* __restrict__ cntc, const int* __restrict__ off,
        ushort* __restrict__ Yc) {
    int b = blockIdx.x;
    int xcd = b & 7, slot = b >> 3;
    int e, xblk, yblk;
    if (slot < 128) { e = xcd; xblk = slot >> 1; yblk = slot & 1; }
    else { int s = slot - 128; e = 8; xblk = (xcd << 3) + (s >> 1); yblk = s & 1; }
    int cn = cntc[e];
    int m0 = xblk * 128;
    if (m0 >= cn) return;
    int n0 = yblk * 256;
    int oe = off[e];
    const ushort* w2e = w2t + (size_t)e * Dd * Hh;

    __shared__ ushort As[128 * 64];
    __shared__ ushort Bs[256 * 64];

    int tid = threadIdx.x;
    int lane = tid & 63, wave = tid >> 6;
    int wm = (wave & 1) * 64, wn = (wave >> 1) * 128;
    int col15 = lane & 15, quad = lane >> 4;
    int lr = lane >> 3;
    int lcx = ((lane & 7) ^ lr) * 8;

    const ushort* gA[4];
    const ushort* gB[8];
#pragma unroll
    for (int i = 0; i < 4; ++i)
        gA[i] = Hbuf + (size_t)(oe + m0 + (wave * 4 + i) * 8 + lr) * Hh + lcx;
#pragma unroll
    for (int i = 0; i < 8; ++i)
        gB[i] = w2e + (size_t)(n0 + (wave * 8 + i) * 8 + lr) * Hh + lcx;

    f32x4 acc[4][8];
#pragma unroll
    for (int a = 0; a < 4; ++a)
#pragma unroll
        for (int b2 = 0; b2 < 8; ++b2) acc[a][b2] = (f32x4){0.f, 0.f, 0.f, 0.f};

#pragma unroll
    for (int kb = 0; kb < Hh; kb += 64) {
#pragma unroll
        for (int i = 0; i < 4; ++i)
            __builtin_amdgcn_global_load_lds((const AS1 void*)(gA[i] + kb), (AS3 void*)(As + (wave * 4 + i) * 512), 16, 0, 0);
#pragma unroll
        for (int i = 0; i < 8; ++i)
            __builtin_amdgcn_global_load_lds((const AS1 void*)(gB[i] + kb), (AS3 void*)(Bs + (wave * 8 + i) * 512), 16, 0, 0);
        __syncthreads();
#pragma unroll
        for (int ks = 0; ks < 2; ++ks) {
            int px = ((ks * 4 + quad) ^ (col15 & 7)) * 8;
            short8 a[4], b2[8];
#pragma unroll
            for (int mi = 0; mi < 4; ++mi)
                a[mi] = *(const short8*)&As[(wm + mi * 16 + col15) * 64 + px];
#pragma unroll
            for (int ni = 0; ni < 8; ++ni)
                b2[ni] = *(const short8*)&Bs[(wn + ni * 16 + col15) * 64 + px];
#pragma unroll
            for (int mi = 0; mi < 4; ++mi)
#pragma unroll
                for (int ni = 0; ni < 8; ++ni)
                    acc[mi][ni] = __builtin_amdgcn_mfma_f32_16x16x32_bf16(a[mi], b2[ni], acc[mi][ni], 0, 0, 0);
        }
        __syncthreads();
    }

#pragma unroll
    for (int mi = 0; mi < 4; ++mi)
#pragma unroll
        for (int r = 0; r < 4; ++r) {
            int sl2 = m0 + wm + mi * 16 + quad * 4 + r;
            if (sl2 < cn) {
                size_t rowb = (size_t)(oe + sl2) * Dd;
#pragma unroll
                for (int ni = 0; ni < 8; ++ni)
                    Yc[rowb + n0 + wn + ni * 16 + col15] = f2bf(acc[mi][ni][r]);
            }
        }
}

// ---------- combine: out[t] = g0*Yc[s0] + g1*Yc[s1] + Yc[shared+t] ----------
__global__ __launch_bounds__(256) void combine_kernel(const ushort* __restrict__ Yc,
        const int* __restrict__ slotp, const float* __restrict__ pg,
        const int* __restrict__ off, float* __restrict__ out) {
    int g = blockIdx.x * 256 + threadIdx.x;
    int t = g >> 6;
    int c = (g & 63) * 8;
    int p0 = slotp[t * 2], p1 = slotp[t * 2 + 1];
    float g0 = pg[t * 2], g1 = pg[t * 2 + 1];
    int s0 = off[p0 >> 16] + (p0 & 0xffff);
    int s1 = off[p1 >> 16] + (p1 & 0xffff);
    int s2 = off[8] + t;
    short8 a = *(const short8*)(Yc + (size_t)s0 * Dd + c);
    short8 b = *(const short8*)(Yc + (size_t)s1 * Dd + c);
    short8 d = *(const short8*)(Yc + (size_t)s2 * Dd + c);
    float o[8];
#pragma unroll
    for (int i = 0; i < 8; ++i)
        o[i] = g0 * bf2f(a[i]) + g1 * bf2f(b[i]) + bf2f(d[i]);
    float* dst = out + (size_t)t * Dd + c;
    *(float4*)dst = (float4){o[0], o[1], o[2], o[3]};
    *(float4*)(dst + 4) = (float4){o[4], o[5], o[6], o[7]};
}

extern "C" void kernel_launch(void* const* d_in, const int* in_sizes, int n_in,
                              void* d_out, int out_size, void* d_ws, size_t ws_size,
                              hipStream_t stream) {
    (void)in_sizes; (void)n_in; (void)out_size; (void)ws_size;
    const float* x    = (const float*)d_in[0];
    const float* gw   = (const float*)d_in[1];
    const float* bias = (const float*)d_in[2];
    const float* w1   = (const float*)d_in[3];
    const float* w3   = (const float*)d_in[4];
    const float* w2   = (const float*)d_in[5];
    const float* sw1  = (const float*)d_in[6];
    const float* sw3  = (const float*)d_in[7];
    const float* sw2  = (const float*)d_in[8];
    float* out = (float*)d_out;

    char* ws = (char*)d_ws;
    ushort* xb    = (ushort*)(ws + OFF_XB);
    ushort* w13t  = (ushort*)(ws + OFF_W13T);
    ushort* w2t   = (ushort*)(ws + OFF_W2T);
    ushort* Hbuf  = (ushort*)(ws + OFF_HBUF);
    ushort* Yc    = (ushort*)(ws + OFF_YC);
    int*    tok   = (int*)(ws + OFF_TOK);
    int*    slotp = (int*)(ws + OFF_SLOTP);
    float*  pg    = (float*)(ws + OFF_PG);
    int*    cnt   = (int*)(ws + OFF_CNT);
    int*    off   = (int*)(ws + OFF_OFFS);
    int*    cntc  = off + 16;

    hipMemsetAsync(cnt, 0, 1024, stream);

    preproc_kernel<<<14080, 256, 0, stream>>>(x, gw, bias, w1, sw1, w3, sw3, w2, sw2,
                                              w13t, w2t, cnt, tok, slotp, pg, xb, off, cntc);
    stage1_kernel<<<9216, 256, 0, stream>>>(xb, w13t, tok, cntc, off, Hbuf);
    stage2_kernel<<<1152, 256, 0, stream>>>(Hbuf, w2t, cntc, off, Yc);
    combine_kernel<<<2048, 256, 0, stream>>>(Yc, slotp, pg, off, out);
}